// Round 7
// baseline (306.937 us; speedup 1.0000x reference)
//
#include <hip/hip_runtime.h>
#include <hip/hip_bf16.h>
#include <math.h>

#define N_GRAPHS 256
#define NODES_PER 100
#define NN (N_GRAPHS * NODES_PER)   // 25600
#define DEG 8
#define FD 128
#define LAT 256
#define HFD 512                      // HEADS * F_DIM
#define NEG_SLOPE 0.2f

typedef _Float16 half8 __attribute__((ext_vector_type(8)));
typedef float float4v __attribute__((ext_vector_type(4)));

// XCD-contiguous chunk swizzle; requires total % 8 == 0 (bijective)
__device__ __forceinline__ int xcd_swz(int bid, int total) {
    int q = total >> 3;
    return (bid & 7) * q + (bid >> 3);
}

// async global->LDS, 16 bytes per lane; lds base must be wave-uniform
__device__ __forceinline__ void gload_lds16(const _Float16* g, _Float16* l) {
    __builtin_amdgcn_global_load_lds(
        (const __attribute__((address_space(1))) unsigned int*)g,
        (__attribute__((address_space(3))) unsigned int*)l, 16, 0, 0);
}

// ---------------------------------------------------------------- g0 = z @ W0 + b0   [256,128]
__global__ void g0_kernel(const float* __restrict__ z, const float* __restrict__ W0,
                          const float* __restrict__ b0, float* __restrict__ g0) {
    __shared__ float s_z[LAT];
    int g = blockIdx.x;
    int j = threadIdx.x;
    s_z[j]       = z[g * LAT + j];
    s_z[j + 128] = z[g * LAT + 128 + j];
    __syncthreads();
    float acc = 0.f;
    #pragma unroll 8
    for (int k = 0; k < LAT; ++k)
        acc += s_z[k] * W0[k * FD + j];
    g0[g * FD + j] = acc + b0[j];
}

// ---------------------------------------------------------------- x1 = relu(concat(g0[batch], pos[order]))  [N,256] fp16
__global__ void build_x1_kernel(const float* __restrict__ g0,
                                const int* __restrict__ batch, _Float16* __restrict__ x1) {
    __shared__ int s_b, s_ord;
    int i = blockIdx.x;
    int t = threadIdx.x;
    if (t == 0) {
        int b = batch[i];
        int lo = 0, hi = i;
        while (lo < hi) { int mid = (lo + hi) >> 1; if (batch[mid] < b) lo = mid + 1; else hi = mid; }
        s_b = b;
        s_ord = i - lo;
    }
    __syncthreads();
    float v;
    if (t < 128) {
        v = g0[s_b * FD + t];
    } else {
        int j = t - 128;
        int j2 = j >> 1;
        float freq = expf(-(float)j2 * 0.1439115683f);   // ln(10000)/64
        float ang = (float)s_ord * freq;
        v = (j & 1) ? cosf(ang) : sinf(ang);
    }
    x1[(size_t)i * 256 + t] = (_Float16)fmaxf(v, 0.f);
}

// ---------------------------------------------------------------- merged weight transpose+convert (4 matrices, one launch)
__global__ void wconv_all_kernel(const float* __restrict__ W1, const float* __restrict__ W2,
                                 const float* __restrict__ W3, const float* __restrict__ Wg,
                                 _Float16* __restrict__ W1t, _Float16* __restrict__ W2t,
                                 _Float16* __restrict__ W3t, _Float16* __restrict__ Wgt) {
    __shared__ float tile[32][33];
    int b = blockIdx.x;
    const float* in; _Float16* out; int K, Nw, tid2;
    if (b < 128)      { in = W1; out = W1t; K = 256; Nw = 512; tid2 = b; }
    else if (b < 384) { in = W2; out = W2t; K = 512; Nw = 512; tid2 = b - 128; }
    else if (b < 640) { in = W3; out = W3t; K = 512; Nw = 512; tid2 = b - 384; }
    else              { in = Wg; out = Wgt; K = 512; Nw = 128; tid2 = b - 640; }
    int nxt = Nw / 32;
    int nb = (tid2 % nxt) * 32, kb = (tid2 / nxt) * 32;
    int tx = threadIdx.x & 31, ty = threadIdx.x >> 5;
    #pragma unroll
    for (int r = 0; r < 4; ++r)
        tile[ty + 8 * r][tx] = in[(size_t)(kb + ty + 8 * r) * Nw + nb + tx];
    __syncthreads();
    #pragma unroll
    for (int r = 0; r < 4; ++r)
        out[(size_t)(nb + ty + 8 * r) * K + kb + tx] = (_Float16)tile[tx][ty + 8 * r];
}

// ---------------------------------------------------------------- fp16 MFMA GEMM, global_load_lds staging (m97 structure)
// LDS layout (linear): As slot (r, q) holds global (r, q ^ ((r>>1)&3)) — achieved by
// pre-swizzling the per-lane GLOBAL source (XOR involution); ds_read applies the same XOR.
// Tile = 128 rows x 32 halves = 8 KB; 256 threads x 16B covers half, so TWO DMA loads
// per buffer per K-step (rows 0-63, rows 64-127). [round-6 bug: only one was issued]
// MODE 0: Y fp16 + fused s,d epilogue (nbx=4, col-block == head).
// MODE 1: fused out = relu(acc+bg) @ Wf + bf -> out[N][5]  (nbx=1, no Y write).
template <int MODE>
__global__ __launch_bounds__(256) void hgemm_kernel(
    const _Float16* __restrict__ X,   // [M][K] row-major
    const _Float16* __restrict__ Wt,  // [N][K] row-major
    const float* __restrict__ bias,   // MODE1: bg[128]
    const float* __restrict__ a_src,  // MODE0: [4][128]
    const float* __restrict__ a_dst,  // MODE0
    float* __restrict__ sbuf,         // MODE0: [NN][4]
    float* __restrict__ dbuf,         // MODE0
    const float* __restrict__ Wf,     // MODE1: [128][5]
    const float* __restrict__ bfv,    // MODE1: [5]
    void* __restrict__ Yv,
    int K, int ldy, int nbx) {
    __shared__ __align__(16) _Float16 As[128 * 32];
    __shared__ __align__(16) _Float16 Bs[128 * 32];
    __shared__ float red[5][128][2];
    const int lin = xcd_swz(blockIdx.x, gridDim.x);
    const int row0 = (lin / nbx) * 128;
    const int col0 = (lin % nbx) * 128;
    const int tid  = threadIdx.x;
    const int lane = tid & 63;
    const int wave = tid >> 6;
    const int wm = wave >> 1;
    const int wn = wave & 1;

    // staging: load 0 -> LDS halves [tid*8,+8) (rows 0-63); load 1 -> [2048+tid*8,+8) (rows 64-127)
    const int srow = tid >> 2;                       // 0..63
    const int sq   = (tid & 3) ^ ((tid >> 3) & 3);   // pre-swizzled k-group; same for row+64
    const _Float16* gA0 = X  + (size_t)(row0 + srow) * K + sq * 8;
    const _Float16* gB0 = Wt + (size_t)(col0 + srow) * K + sq * 8;
    const _Float16* gA1 = gA0 + (size_t)64 * K;
    const _Float16* gB1 = gB0 + (size_t)64 * K;
    _Float16* ldsA0 = &As[wave * 512];               // wave-uniform bases
    _Float16* ldsA1 = &As[2048 + wave * 512];
    _Float16* ldsB0 = &Bs[wave * 512];
    _Float16* ldsB1 = &Bs[2048 + wave * 512];

    const int kq  = lane >> 4;
    const int l15 = lane & 15;

    float4v acc[4][4];
    #pragma unroll
    for (int i = 0; i < 4; ++i)
        #pragma unroll
        for (int j = 0; j < 4; ++j)
            acc[i][j] = (float4v){0.f, 0.f, 0.f, 0.f};

    const int nk = K >> 5;
    for (int ks = 0; ks < nk; ++ks) {
        gload_lds16(gA0 + ks * 32, ldsA0);
        gload_lds16(gA1 + ks * 32, ldsA1);
        gload_lds16(gB0 + ks * 32, ldsB0);
        gload_lds16(gB1 + ks * 32, ldsB1);
        __syncthreads();                 // drains vmcnt -> tile ready
        half8 af[4], bfr[4];
        #pragma unroll
        for (int mi = 0; mi < 4; ++mi) {
            int r = wm * 64 + mi * 16 + l15;
            af[mi] = *(const half8*)&As[r * 32 + ((kq ^ ((r >> 1) & 3)) * 8)];
        }
        #pragma unroll
        for (int ni = 0; ni < 4; ++ni) {
            int c = wn * 64 + ni * 16 + l15;
            bfr[ni] = *(const half8*)&Bs[c * 32 + ((kq ^ ((c >> 1) & 3)) * 8)];
        }
        #pragma unroll
        for (int mi = 0; mi < 4; ++mi)
            #pragma unroll
            for (int ni = 0; ni < 4; ++ni)
                acc[mi][ni] = __builtin_amdgcn_mfma_f32_16x16x32_f16(af[mi], bfr[ni], acc[mi][ni], 0, 0, 0);
        __syncthreads();                 // all reads done before next stage
    }

    // C/D layout: col = l15, row = (lane>>4)*4 + j  (within each 16x16 tile)
    if (MODE == 0) {
        const int h = col0 >> 7;   // head index
        float asv[4], adv[4];
        #pragma unroll
        for (int ni = 0; ni < 4; ++ni) {
            int ch = wn * 64 + ni * 16 + l15;
            asv[ni] = a_src[h * FD + ch];
            adv[ni] = a_dst[h * FD + ch];
        }
        #pragma unroll
        for (int mi = 0; mi < 4; ++mi) {
            int rb = row0 + wm * 64 + mi * 16 + ((lane >> 4) << 2);
            #pragma unroll
            for (int j = 0; j < 4; ++j) {
                float ps = 0.f, pd = 0.f;
                #pragma unroll
                for (int ni = 0; ni < 4; ++ni) {
                    float v = acc[mi][ni][j];
                    int c = col0 + wn * 64 + ni * 16 + l15;
                    ((_Float16*)Yv)[(size_t)(rb + j) * ldy + c] = (_Float16)v;
                    ps += v * asv[ni];
                    pd += v * adv[ni];
                }
                #pragma unroll
                for (int m = 8; m >= 1; m >>= 1) {
                    ps += __shfl_xor(ps, m);
                    pd += __shfl_xor(pd, m);
                }
                if (l15 == 0) {
                    int rloc = wm * 64 + mi * 16 + ((lane >> 4) << 2) + j;
                    red[0][rloc][wn] = ps;
                    red[1][rloc][wn] = pd;
                }
            }
        }
        __syncthreads();
        if (tid < 128) {
            sbuf[(size_t)(row0 + tid) * 4 + h] = red[0][tid][0] + red[0][tid][1];
            dbuf[(size_t)(row0 + tid) * 4 + h] = red[1][tid][0] + red[1][tid][1];
        }
    } else {
        float bgv[4], wf[4][5];
        #pragma unroll
        for (int ni = 0; ni < 4; ++ni) {
            int c = wn * 64 + ni * 16 + l15;
            bgv[ni] = bias[c];
            #pragma unroll
            for (int q = 0; q < 5; ++q) wf[ni][q] = Wf[c * 5 + q];
        }
        #pragma unroll
        for (int mi = 0; mi < 4; ++mi) {
            #pragma unroll
            for (int j = 0; j < 4; ++j) {
                float vr[4];
                #pragma unroll
                for (int ni = 0; ni < 4; ++ni)
                    vr[ni] = fmaxf(acc[mi][ni][j] + bgv[ni], 0.f);
                #pragma unroll
                for (int q = 0; q < 5; ++q) {
                    float p = vr[0] * wf[0][q] + vr[1] * wf[1][q] + vr[2] * wf[2][q] + vr[3] * wf[3][q];
                    #pragma unroll
                    for (int m = 8; m >= 1; m >>= 1) p += __shfl_xor(p, m);
                    if (l15 == 0) {
                        int rloc = wm * 64 + mi * 16 + ((lane >> 4) << 2) + j;
                        red[q][rloc][wn] = p;
                    }
                }
            }
        }
        __syncthreads();
        if (tid < 128) {
            float* o = (float*)Yv;
            #pragma unroll
            for (int q = 0; q < 5; ++q)
                o[(size_t)(row0 + tid) * 5 + q] = red[q][tid][0] + red[q][tid][1] + bfv[q];
        }
    }
}

// ---------------------------------------------------------------- attention + aggregation (wave-per-node, fp16)
__global__ void agg_kernel(const _Float16* __restrict__ xl,
                           const float* __restrict__ s, const float* __restrict__ d,
                           const int* __restrict__ esrc,
                           const float* __restrict__ bias,
                           _Float16* __restrict__ xout) {
    int wave = threadIdx.x >> 6;
    int lane = threadIdx.x & 63;
    int blk = xcd_swz(blockIdx.x, gridDim.x);
    int i = blk * 4 + wave;
    int h = lane >> 4;

    int sk = (lane < 8) ? esrc[i * DEG + lane] : i;
    int srcs[9];
    #pragma unroll
    for (int k = 0; k < 9; ++k) srcs[k] = __shfl(sk, k);

    float dh = d[i * 4 + h];
    float e[9];
    float m = -1e30f;
    #pragma unroll
    for (int k = 0; k < 9; ++k) {
        float v = s[srcs[k] * 4 + h] + dh;
        v = (v >= 0.f) ? v : NEG_SLOPE * v;
        e[k] = v;
        m = fmaxf(m, v);
    }
    float den = 0.f;
    #pragma unroll
    for (int k = 0; k < 9; ++k) { e[k] = __expf(e[k] - m); den += e[k]; }
    float inv = 1.f / (den + 1e-16f);

    int c0 = lane * 8;
    float acc[8] = {};
    #pragma unroll
    for (int k = 0; k < 9; ++k) {
        half8 x = *(const half8*)&xl[(size_t)srcs[k] * HFD + c0];
        float a = e[k] * inv;
        #pragma unroll
        for (int j = 0; j < 8; ++j) acc[j] += a * (float)x[j];
    }
    float4v b0 = *(const float4v*)&bias[c0];
    float4v b1 = *(const float4v*)&bias[c0 + 4];
    half8 o;
    #pragma unroll
    for (int j = 0; j < 4; ++j) {
        o[j]     = (_Float16)fmaxf(acc[j] + b0[j], 0.f);
        o[j + 4] = (_Float16)fmaxf(acc[j + 4] + b1[j], 0.f);
    }
    *(half8*)&xout[(size_t)i * HFD + c0] = o;
}

// ----------------------------------------------------------------
extern "C" void kernel_launch(void* const* d_in, const int* in_sizes, int n_in,
                              void* d_out, int out_size, void* d_ws, size_t ws_size,
                              hipStream_t stream) {
    const float* z    = (const float*)d_in[0];
    const int*  eidx  = (const int*)d_in[1];
    const int*  batch = (const int*)d_in[2];
    const float* W0  = (const float*)d_in[3];
    const float* b0  = (const float*)d_in[4];
    const float* W1  = (const float*)d_in[5];
    const float* as1 = (const float*)d_in[6];
    const float* ad1 = (const float*)d_in[7];
    const float* b1  = (const float*)d_in[8];
    const float* W2  = (const float*)d_in[9];
    const float* as2 = (const float*)d_in[10];
    const float* ad2 = (const float*)d_in[11];
    const float* b2  = (const float*)d_in[12];
    const float* W3  = (const float*)d_in[13];
    const float* as3 = (const float*)d_in[14];
    const float* ad3 = (const float*)d_in[15];
    const float* b3  = (const float*)d_in[16];
    const float* Wg  = (const float*)d_in[17];
    const float* bg  = (const float*)d_in[18];
    const float* Wf  = (const float*)d_in[19];
    const float* bfv = (const float*)d_in[20];
    float* out = (float*)d_out;

    float* ws   = (float*)d_ws;
    float* g0   = ws;                          // 32768
    float* sbuf = g0 + 32768;                  // NN*4
    float* dbuf = sbuf + (size_t)NN * 4;       // NN*4
    _Float16* Yh  = (_Float16*)(dbuf + (size_t)NN * 4);    // NN*512 fp16
    _Float16* Xh  = Yh + (size_t)NN * 512;     // NN*512 fp16
    _Float16* W1t = Xh + (size_t)NN * 512;     // 512*256
    _Float16* W2t = W1t + 512 * 256;           // 512*512
    _Float16* W3t = W2t + 512 * 512;           // 512*512
    _Float16* Wgt = W3t + 512 * 512;           // 128*512

    g0_kernel<<<N_GRAPHS, FD, 0, stream>>>(z, W0, b0, g0);
    build_x1_kernel<<<NN, 256, 0, stream>>>(g0, batch, Xh);
    wconv_all_kernel<<<704, 256, 0, stream>>>(W1, W2, W3, Wg, W1t, W2t, W3t, Wgt);

    const int nbL = (NN / 128) * (HFD / 128);  // 800 blocks
    const int nbH = (NN / 128) * (FD / 128);   // 200 blocks

    // ---- layer 1 (K=256): GEMM + fused s,d
    hgemm_kernel<0><<<nbL, 256, 0, stream>>>(Xh, W1t, nullptr, as1, ad1, sbuf, dbuf, nullptr, nullptr, Yh, 256, HFD, HFD / 128);
    agg_kernel<<<NN / 4, 256, 0, stream>>>(Yh, sbuf, dbuf, eidx, b1, Xh);

    // ---- layer 2 (K=512)
    hgemm_kernel<0><<<nbL, 256, 0, stream>>>(Xh, W2t, nullptr, as2, ad2, sbuf, dbuf, nullptr, nullptr, Yh, 512, HFD, HFD / 128);
    agg_kernel<<<NN / 4, 256, 0, stream>>>(Yh, sbuf, dbuf, eidx, b2, Xh);

    // ---- layer 3 (K=512)
    hgemm_kernel<0><<<nbL, 256, 0, stream>>>(Xh, W3t, nullptr, as3, ad3, sbuf, dbuf, nullptr, nullptr, Yh, 512, HFD, HFD / 128);
    agg_kernel<<<NN / 4, 256, 0, stream>>>(Yh, sbuf, dbuf, eidx, b3, Xh);

    // ---- gather head + final projection fused: out = relu(x@Wg+bg) @ Wf + bf
    hgemm_kernel<1><<<nbH, 256, 0, stream>>>(Xh, Wgt, bg, nullptr, nullptr, nullptr, nullptr, Wf, bfv, out, 512, 5, FD / 128);
}